// Round 11
// baseline (227.476 us; speedup 1.0000x reference)
//
#include <hip/hip_runtime.h>
#include <cstdint>
#include <cstddef>

typedef unsigned short u16;
typedef unsigned int   u32;
typedef __attribute__((ext_vector_type(8))) short bf16x8;
typedef __attribute__((ext_vector_type(4))) float f32x4;

static constexpr int kQ = 300;
static constexpr int kL2 = 21760;

__device__ __forceinline__ u16 bf16_rne(float f) {
    u32 u = __float_as_uint(f);
    u += 0x7FFFu + ((u >> 16) & 1u);
    return (u16)(u >> 16);
}
__device__ __forceinline__ u32 pack2(float lo, float hi) {
    return (u32)bf16_rne(lo) | ((u32)bf16_rne(hi) << 16);
}
__device__ __forceinline__ float lo16(u32 u) { return __uint_as_float(u << 16); }
__device__ __forceinline__ float hi16(u32 u) { return __uint_as_float(u & 0xFFFF0000u); }

// ---------------------------------------------------------------------------
// MFMA bf16 GEMM: C[M,256] = A[M,256] @ W[256,256]^T + bias, opt rowmask.
// BM=64, BN=128, BK=32, 256 threads (4 waves 2m x 2n), wave tile 32x64.
// Double-buffered LDS, reg-staged, 1 barrier/step. Rotation swizzle:
//   chunk(row,sub) = sub*NR + ((row + 2*sub) mod NR)
// A_F32: A read as f32, packed to bf16 during staging.
// OUT_BF16: bf16 output via LDS bounce; else direct f32 stores.
// MERGED_OUT: blocks with blockIdx.x >= 600 run the small f32 out-GEMM
//   (out = (out_part[kh=0]+out_part[kh=1]) @ Wf^T + bias) on 64x64 tiles.
// ---------------------------------------------------------------------------
#define GLOAD(kt) { \
    const int k0 = (kt) * 32; \
    if constexpr (A_F32) { \
        const float* p = (const float*)Aptr + (size_t)(m0 + arow) * 256 + k0 + asub * 8; \
        ra0 = *(const float4*)p; ra1 = *(const float4*)(p + 4); \
    } else { \
        rav = *(const uint4*)((const u16*)Aptr + (size_t)(m0 + arow) * 256 + k0 + asub * 8); \
    } \
    rb0 = *(const uint4*)(W + (size_t)(n0 + b0row) * 256 + k0 + bsub * 8); \
    rb1 = *(const uint4*)(W + (size_t)(n0 + b1row) * 256 + k0 + bsub * 8); }

#define GSTORE(buf) { \
    u16* As = S + (buf) * 6144; \
    u16* Bs = As + 2048; \
    const int ac = asub * 64 + ((arow + 2 * asub) & 63); \
    if constexpr (A_F32) { \
        uint4 o; \
        o.x = pack2(ra0.x, ra0.y); o.y = pack2(ra0.z, ra0.w); \
        o.z = pack2(ra1.x, ra1.y); o.w = pack2(ra1.z, ra1.w); \
        *(uint4*)(As + (ac << 3)) = o; \
    } else { \
        *(uint4*)(As + (ac << 3)) = rav; \
    } \
    *(uint4*)(Bs + ((bsub * 128 + ((b0row + 2 * bsub) & 127)) << 3)) = rb0; \
    *(uint4*)(Bs + ((bsub * 128 + ((b1row + 2 * bsub) & 127)) << 3)) = rb1; }

template<bool A_F32, bool OUT_BF16, bool MERGED_OUT>
__global__ __launch_bounds__(256)
void gemm_bf16(const void* __restrict__ Aptr, const u16* __restrict__ W,
               const float* __restrict__ bias, void* __restrict__ Cout,
               const unsigned char* __restrict__ rowmask,
               const float* __restrict__ Wf,        // f32 Wout (out path)
               const float* __restrict__ opart,     // out_part (out path)
               float* __restrict__ C2)              // out (out path)
{
    __shared__ u16 S[12288];           // 24KB pool
    const int tid = threadIdx.x;

    if constexpr (MERGED_OUT) {
        if (blockIdx.x >= 600) {
            // ---- small f32 out-GEMM: 64x64 tiles, M=600 ----
            float (*As2)[68] = reinterpret_cast<float(*)[68]>(S);
            float (*Ws2)[68] = reinterpret_cast<float(*)[68]>((char*)S + 8704);
            const int t20 = blockIdx.x - 600;           // 0..19
            const int m0o = (t20 % 10) * 64;
            const int nq  = (t20 / 10) * 2 + blockIdx.y;
            const int n0o = nq * 64;
            const int tx = tid & 15, ty = tid >> 4;
            const size_t KQS = (size_t)600 * 256;
            float acc[4][4] = {};
            for (int k0 = 0; k0 < 256; k0 += 32) {
#pragma unroll
                for (int i = 0; i < 2; i++) {
                    int t = tid + i * 256;
                    int rr = t >> 3;
                    int c4 = (t & 7) << 2;
                    int ra = min(m0o + rr, 599);
                    const float* p = opart + (size_t)ra * 256 + k0 + c4;
                    float4 v0 = *(const float4*)p;
                    float4 v1 = *(const float4*)(p + KQS);
                    float4 va;
                    va.x = v0.x + v1.x; va.y = v0.y + v1.y;
                    va.z = v0.z + v1.z; va.w = v0.w + v1.w;
                    As2[c4 + 0][rr] = va.x; As2[c4 + 1][rr] = va.y;
                    As2[c4 + 2][rr] = va.z; As2[c4 + 3][rr] = va.w;
                    float4 vw = *(const float4*)(Wf + (size_t)(n0o + rr) * 256 + k0 + c4);
                    Ws2[c4 + 0][rr] = vw.x; Ws2[c4 + 1][rr] = vw.y;
                    Ws2[c4 + 2][rr] = vw.z; Ws2[c4 + 3][rr] = vw.w;
                }
                __syncthreads();
#pragma unroll
                for (int kk = 0; kk < 32; kk++) {
                    float4 a = *(const float4*)&As2[kk][ty * 4];
                    float4 wv4 = *(const float4*)&Ws2[kk][tx * 4];
                    float av[4] = {a.x, a.y, a.z, a.w};
                    float wv[4] = {wv4.x, wv4.y, wv4.z, wv4.w};
#pragma unroll
                    for (int i = 0; i < 4; i++)
#pragma unroll
                        for (int jj = 0; jj < 4; jj++)
                            acc[i][jj] += av[i] * wv[jj];
                }
                __syncthreads();
            }
#pragma unroll
            for (int i = 0; i < 4; i++) {
                int rr = m0o + ty * 4 + i;
                if (rr >= 600) continue;
                int n = n0o + tx * 4;
                float4 o;
                o.x = acc[i][0] + bias[n + 0];
                o.y = acc[i][1] + bias[n + 1];
                o.z = acc[i][2] + bias[n + 2];
                o.w = acc[i][3] + bias[n + 3];
                *(float4*)(C2 + (size_t)rr * 256 + n) = o;
            }
            return;
        }
    }

    const int m0 = blockIdx.x * 64;
    const int n0 = blockIdx.y * 128;
    const int lane = tid & 63;
    const int w = tid >> 6;
    const int wm = w & 1, wn = w >> 1;
    const int g = lane >> 4, r = lane & 15;

    const int arow = tid >> 2, asub = tid & 3;
    const int b0row = tid >> 2;
    const int b1row = 64 + (tid >> 2);
    const int bsub = tid & 3;

    f32x4 acc[2][4];
#pragma unroll
    for (int i = 0; i < 2; i++)
#pragma unroll
        for (int j = 0; j < 4; j++)
            acc[i][j] = (f32x4){0.f, 0.f, 0.f, 0.f};

    float4 ra0, ra1; uint4 rav; uint4 rb0, rb1;

    GLOAD(0);
    GSTORE(0);
    for (int kt = 0; kt < 8; ++kt) {
        if (kt < 7) GLOAD(kt + 1);
        __syncthreads();
        const u16* As = S + (kt & 1) * 6144;
        const u16* Bs = As + 2048;
        bf16x8 af[2], bf[4];
#pragma unroll
        for (int mf = 0; mf < 2; ++mf) {
            int X = wm * 32 + mf * 16 + r;
            af[mf] = *(const bf16x8*)(As + ((g * 64 + ((X + 2 * g) & 63)) << 3));
        }
#pragma unroll
        for (int nf = 0; nf < 4; ++nf) {
            int X = wn * 64 + nf * 16 + r;
            bf[nf] = *(const bf16x8*)(Bs + ((g * 128 + ((X + 2 * g) & 127)) << 3));
        }
#pragma unroll
        for (int mf = 0; mf < 2; ++mf)
#pragma unroll
            for (int nf = 0; nf < 4; ++nf)
                acc[mf][nf] = __builtin_amdgcn_mfma_f32_16x16x32_bf16(
                    af[mf], bf[nf], acc[mf][nf], 0, 0, 0);
        if (kt < 7) GSTORE((kt + 1) & 1);
    }

    if constexpr (!OUT_BF16) {
        float* C = (float*)Cout;
#pragma unroll
        for (int nf = 0; nf < 4; ++nf) {
            int ng = n0 + wn * 64 + nf * 16 + r;
            float bb = bias[ng];
#pragma unroll
            for (int mf = 0; mf < 2; ++mf) {
                int mg = m0 + wm * 32 + mf * 16 + g * 4;
#pragma unroll
                for (int reg = 0; reg < 4; ++reg) {
                    float z = 1.f;
                    if (rowmask && rowmask[mg + reg]) z = 0.f;
                    C[(size_t)(mg + reg) * 256 + ng] = (acc[mf][nf][reg] + bb) * z;
                }
            }
        }
    } else {
        u16* C = (u16*)Cout;
#pragma unroll
        for (int round = 0; round < 2; ++round) {
            __syncthreads();
            if (wn == round) {
#pragma unroll
                for (int nf = 0; nf < 4; ++nf) {
                    int col = nf * 16 + r;
                    float bb = bias[n0 + round * 64 + col];
#pragma unroll
                    for (int mf = 0; mf < 2; ++mf) {
                        int row0 = wm * 32 + mf * 16 + g * 4;
#pragma unroll
                        for (int reg = 0; reg < 4; ++reg) {
                            float z = 1.f;
                            if (rowmask && rowmask[m0 + row0 + reg]) z = 0.f;
                            S[(row0 + reg) * 64 + col] =
                                bf16_rne((acc[mf][nf][reg] + bb) * z);
                        }
                    }
                }
            }
            __syncthreads();
#pragma unroll
            for (int i = 0; i < 2; ++i) {
                int c = tid + i * 256;
                int row = c >> 3, cc = c & 7;
                *(uint4*)(C + (size_t)(m0 + row) * 256 + n0 + round * 64 + cc * 8) =
                    *(const uint4*)(S + row * 64 + cc * 8);
            }
        }
    }
}

// ---------------------------------------------------------------------------
// Merged prep kernel. Blocks 0..63: convert Wv/Wout to bf16.
// Blocks 64..663: per-(b,q) params (aw/ob GEMV + softmaxes + boxes).
// ---------------------------------------------------------------------------
__global__ __launch_bounds__(256)
void prep_kernel(const float* __restrict__ Wv, u16* __restrict__ Wv_b,
                 const float* __restrict__ Wout, u16* __restrict__ Wout_b,
                 const float* __restrict__ query,
                 const float* __restrict__ Wattn, const float* __restrict__ battn,
                 const float* __restrict__ Wbox,  const float* __restrict__ bbox,
                 const float* __restrict__ ref_windows,
                 const float* __restrict__ vvr,
                 float* __restrict__ params)
{
    if (blockIdx.x < 64) {
        const float* src = (blockIdx.x < 32) ? Wv : Wout;
        u16* dst = (blockIdx.x < 32) ? Wv_b : Wout_b;
        int i = ((blockIdx.x & 31) * 256 + threadIdx.x) * 8;
        float4 a = *(const float4*)(src + i);
        float4 b = *(const float4*)(src + i + 4);
        uint4 o;
        o.x = pack2(a.x, a.y); o.y = pack2(a.z, a.w);
        o.z = pack2(b.x, b.y); o.w = pack2(b.z, b.w);
        *(uint4*)(dst + i) = o;
        return;
    }

    __shared__ float qrow[256];
    __shared__ float awob[256];
    __shared__ float4 boxs[8][4];
    __shared__ float wgts[8][4][4];
    __shared__ float cqds[8][4];

    const int bq = blockIdx.x - 64;
    const int b = bq / kQ;
    const int tid = threadIdx.x;

    if (tid < 64)
        ((float4*)qrow)[tid] = ((const float4*)(query + (size_t)bq * 256))[tid];
    __syncthreads();

    {
        const float* Wrow = (tid < 128) ? (Wattn + (size_t)tid * 256)
                                        : (Wbox + (size_t)(tid - 128) * 256);
        float s = (tid < 128) ? battn[tid] : bbox[tid - 128];
#pragma unroll 8
        for (int d4 = 0; d4 < 64; d4++) {
            float4 wv = ((const float4*)Wrow)[d4];
            float4 qv = ((const float4*)qrow)[d4];
            s += wv.x * qv.x + wv.y * qv.y + wv.z * qv.z + wv.w * qv.w;
        }
        awob[tid] = s;
    }
    __syncthreads();

    if (tid < 8) {
        const int h = tid;
        float m = -1e30f;
        float E[16];
#pragma unroll
        for (int i = 0; i < 16; i++) m = fmaxf(m, awob[h * 16 + i]);
        float Ssum = 0.f;
#pragma unroll
        for (int i = 0; i < 16; i++) { E[i] = expf(awob[h * 16 + i] - m); Ssum += E[i]; }
        float invS16 = 1.f / (16.f * Ssum);
#pragma unroll
        for (int qd = 0; qd < 4; qd++) {
            float Sq = E[qd] + E[4 + qd] + E[8 + qd] + E[12 + qd];
            float inv = 1.f / Sq;
#pragma unroll
            for (int l = 0; l < 4; l++) wgts[h][l][qd] = E[l * 4 + qd] * inv;
            cqds[h][qd] = Sq * invS16;
        }
    }
    if (tid >= 64 && tid < 96) {
        const int t = tid - 64;
        const int h = t >> 2, l = t & 3;
        float4 rw = ((const float4*)ref_windows)[bq];
        float ob0 = awob[128 + h * 16 + l * 4 + 0];
        float ob1 = awob[128 + h * 16 + l * 4 + 1];
        float ob2 = awob[128 + h * 16 + l * 4 + 2];
        float ob3 = awob[128 + h * 16 + l * 4 + 3];
        float cx = rw.x + ob0 * 0.125f * rw.z;
        float cy = rw.y + ob1 * 0.125f * rw.w;
        float sx = fmaxf(rw.z + ob2 * 0.125f * rw.z, 0.f);
        float sy = fmaxf(rw.w + ob3 * 0.125f * rw.w, 0.f);
        float vrx = vvr[(b * 4 + l) * 2 + 0];
        float vry = vvr[(b * 4 + l) * 2 + 1];
        boxs[h][l] = make_float4(cx * vrx, cy * vry, sx * vrx, sy * vry);
    }
    __syncthreads();

    float* p = params + (size_t)bq * 288;
    if (tid < 32)       ((float4*)p)[tid] = ((float4*)boxs)[tid];
    else if (tid < 64)  ((float4*)p)[tid] = ((float4*)wgts)[tid - 32];
    else if (tid < 72)  ((float4*)p)[tid] = ((float4*)cqds)[tid - 64];
}

// ---------------------------------------------------------------------------
// k-pair sampler: grid 1200 = kh*600 + bq (siblings differ by 600 -> same XCD).
// 512 threads = (pair j 0..15, h 0..7, ch 0..3); each thread samples k=2J,2J+1
// (J = kh*16+j). The pair shares row (ky), qd, lw, c and the whole y-side.
// ---------------------------------------------------------------------------
__global__ __launch_bounds__(512, 4)
void sample_bf16(const u16* __restrict__ valb,
                 const float* __restrict__ params,
                 u16* __restrict__ maskb,          // (B*Q*64, 256) bf16
                 float* __restrict__ out_part)     // (1200, 256), [kh*600+bq]
{
    __shared__ float4 boxs[8][4];
    __shared__ float wgts[8][4][4];
    __shared__ float cqds[8][4];
    __shared__ float warr[8][256];

    const int blk = blockIdx.x;
    const int bq = blk % 600;
    const int kh = blk / 600;
    const int b = bq / kQ;
    const int tid = threadIdx.x;

    if (tid < 72) {
        float4 v = ((const float4*)(params + (size_t)bq * 288))[tid];
        if (tid < 32)      ((float4*)boxs)[tid] = v;
        else if (tid < 64) ((float4*)wgts)[tid - 32] = v;
        else               ((float4*)cqds)[tid - 64] = v;
    }
    __syncthreads();

    const int j = tid >> 5;                 // pair 0..15
    const int h = (tid >> 2) & 7;
    const int ch = tid & 3;
    const int J = kh * 16 + j;              // global pair 0..31
    const int ka = 2 * J;                   // even sample point
    const float kxa = (float)(ka & 7) * 0.125f - 0.4375f;
    const float kxb = kxa + 0.125f;
    const float ky  = (float)(ka >> 3) * 0.125f - 0.4375f;
    const int qd = (((ka >> 5) & 1) << 1) | ((ka >> 2) & 1);

    float acca[8], accb[8];
#pragma unroll
    for (int e = 0; e < 8; e++) { acca[e] = 0.f; accb[e] = 0.f; }

    static constexpr int LW[4]  = {128, 64, 32, 16};
    static constexpr int LST[4] = {0, 16384, 20480, 21504};

#pragma unroll
    for (int l = 0; l < 4; l++) {
        const int Wl = LW[l];
        const u16* vbase = valb + ((size_t)(b * kL2 + LST[l]) << 8) + h * 32 + ch * 8;
        float4 bx = boxs[h][l];
        float lw = wgts[h][l][qd];
        // shared y-side
        float y = (bx.y + ky * bx.w) * Wl - 0.5f;
        float y0f = floorf(y);
        float dy = y - y0f;
        int y0 = (int)y0f, y1 = y0 + 1;
        int y0c = min(max(y0, 0), Wl - 1), y1c = min(max(y1, 0), Wl - 1);
        float vy0 = (y0 >= 0 && y0 < Wl) ? 1.f : 0.f;
        float vy1 = (y1 >= 0 && y1 < Wl) ? 1.f : 0.f;
        float wy0 = (1.f - dy) * vy0 * lw;
        float wy1 = dy * vy1 * lw;
        const u16* rbase0 = vbase + ((size_t)(y0c * Wl) << 8);
        const u16* rbase1 = vbase + ((size_t)(y1c * Wl) << 8);
        // two x-sides
#pragma unroll
        for (int s = 0; s < 2; ++s) {
            float kx = s ? kxb : kxa;
            float* acc = s ? accb : acca;
            float x = (bx.x + kx * bx.z) * Wl - 0.5f;
            float x0f = floorf(x);
            float dx = x - x0f;
            int x0 = (int)x0f, x1 = x0 + 1;
            int x0c = min(max(x0, 0), Wl - 1), x1c = min(max(x1, 0), Wl - 1);
            float vx0 = (x0 >= 0 && x0 < Wl) ? 1.f : 0.f;
            float vx1 = (x1 >= 0 && x1 < Wl) ? 1.f : 0.f;
            float w00 = (1.f - dx) * vx0 * wy0;
            float w10 = dx * vx1 * wy0;
            float w01 = (1.f - dx) * vx0 * wy1;
            float w11 = dx * vx1 * wy1;
            uint4 v00 = *(const uint4*)(rbase0 + ((size_t)x0c << 8));
            uint4 v10 = *(const uint4*)(rbase0 + ((size_t)x1c << 8));
            uint4 v01 = *(const uint4*)(rbase1 + ((size_t)x0c << 8));
            uint4 v11 = *(const uint4*)(rbase1 + ((size_t)x1c << 8));
            acc[0] += w00*lo16(v00.x) + w10*lo16(v10.x) + w01*lo16(v01.x) + w11*lo16(v11.x);
            acc[1] += w00*hi16(v00.x) + w10*hi16(v10.x) + w01*hi16(v01.x) + w11*hi16(v11.x);
            acc[2] += w00*lo16(v00.y) + w10*lo16(v10.y) + w01*lo16(v01.y) + w11*lo16(v11.y);
            acc[3] += w00*hi16(v00.y) + w10*hi16(v10.y) + w01*hi16(v01.y) + w11*hi16(v11.y);
            acc[4] += w00*lo16(v00.z) + w10*lo16(v10.z) + w01*lo16(v01.z) + w11*lo16(v11.z);
            acc[5] += w00*hi16(v00.z) + w10*hi16(v10.z) + w01*hi16(v01.z) + w11*hi16(v11.z);
            acc[6] += w00*lo16(v00.w) + w10*lo16(v10.w) + w01*lo16(v01.w) + w11*lo16(v11.w);
            acc[7] += w00*hi16(v00.w) + w10*hi16(v10.w) + w01*hi16(v01.w) + w11*hi16(v11.w);
        }
    }

    // mask_pre bf16 writes (rows ka, ka+1)
    {
        uint4 oa, ob;
        oa.x = pack2(acca[0], acca[1]); oa.y = pack2(acca[2], acca[3]);
        oa.z = pack2(acca[4], acca[5]); oa.w = pack2(acca[6], acca[7]);
        ob.x = pack2(accb[0], accb[1]); ob.y = pack2(accb[2], accb[3]);
        ob.z = pack2(accb[4], accb[5]); ob.w = pack2(accb[6], accb[7]);
        u16* mrow = maskb + (((size_t)bq * 64 + ka) << 8) + h * 32 + ch * 8;
        *(uint4*)mrow = oa;
        *(uint4*)(mrow + 256) = ob;
    }

    // spatial partial: c shared by the pair; reduce over j within wave, then waves
    {
        const int wave = tid >> 6;
        const int lane = tid & 63;
        float c = cqds[h][qd];
#pragma unroll
        for (int e = 0; e < 8; e++) {
            float v = (acca[e] + accb[e]) * c;
            v += __shfl_xor(v, 32);         // combine the wave's two pair-indices
            if (lane < 32) warr[wave][h * 32 + ch * 8 + e] = v;
        }
    }
    __syncthreads();
    if (tid < 256) {
        float s = 0.f;
#pragma unroll
        for (int wv = 0; wv < 8; wv++) s += warr[wv][tid];
        out_part[(size_t)blk * 256 + tid] = s;
    }
}

// ---------------------------------------------------------------------------
extern "C" void kernel_launch(void* const* d_in, const int* in_sizes, int n_in,
                              void* d_out, int out_size, void* d_ws, size_t ws_size,
                              hipStream_t stream)
{
    const float* query       = (const float*)d_in[0];
    const float* value       = (const float*)d_in[1];
    const unsigned char* v_mask = (const unsigned char*)d_in[3];
    const float* vvr         = (const float*)d_in[5];
    const float* ref_windows = (const float*)d_in[6];
    const float* Wv    = (const float*)d_in[7];
    const float* bv    = (const float*)d_in[8];
    const float* Wbox  = (const float*)d_in[9];
    const float* bbox  = (const float*)d_in[10];
    const float* Wattn = (const float*)d_in[11];
    const float* battn = (const float*)d_in[12];
    const float* Wout  = (const float*)d_in[13];
    const float* bout  = (const float*)d_in[14];

    // workspace layout (bytes, all 16B aligned)
    char* wsp = (char*)d_ws;
    u16* Wv_b    = (u16*)wsp;                 wsp += (size_t)65536 * 2;
    u16* Wout_b  = (u16*)wsp;                 wsp += (size_t)65536 * 2;
    u16* val_b   = (u16*)wsp;                 wsp += (size_t)11141120 * 2;
    u16* mask_b  = (u16*)wsp;                 wsp += (size_t)9830400 * 2;
    float* params   = (float*)wsp;            wsp += (size_t)600 * 288 * 4;
    float* out_part = (float*)wsp;            wsp += (size_t)1200 * 256 * 4;

    float* out  = (float*)d_out;              // 600*256
    float* mask = out + (size_t)600 * 256;    // 38400*256

    // 1) weight conversion + per-query params (one dispatch)
    prep_kernel<<<664, 256, 0, stream>>>(Wv, Wv_b, Wout, Wout_b,
                                         query, Wattn, battn, Wbox, bbox,
                                         ref_windows, vvr, params);
    // 2) val = value(f32) @ Wv^T + bv (fused convert, masked rows -> 0), bf16 out
    gemm_bf16<true, true, false><<<dim3(680, 2), 256, 0, stream>>>(
        value, Wv_b, bv, val_b, v_mask, nullptr, nullptr, nullptr);
    // 3) k-pair sampling -> mask_pre (bf16) + spatial partials
    sample_bf16<<<1200, 512, 0, stream>>>(val_b, params, mask_b, out_part);
    // 4) mask = mask_pre @ Wout^T + bout (f32 out)  +  merged out-GEMM
    gemm_bf16<false, false, true><<<dim3(620, 2), 256, 0, stream>>>(
        mask_b, Wout_b, bout, mask, nullptr, Wout, out_part, out);
}

// Round 12
// 120.503 us; speedup vs baseline: 1.8877x; 1.8877x over previous
//
#include <hip/hip_runtime.h>
#include <cstdint>
#include <cstddef>

typedef unsigned short u16;
typedef unsigned int   u32;
typedef __attribute__((ext_vector_type(8))) short bf16x8;
typedef __attribute__((ext_vector_type(4))) float f32x4;

static constexpr int kQ = 300;
static constexpr int kL2 = 21760;

__device__ __forceinline__ u16 bf16_rne(float f) {
    u32 u = __float_as_uint(f);
    u += 0x7FFFu + ((u >> 16) & 1u);
    return (u16)(u >> 16);
}
__device__ __forceinline__ u32 pack2(float lo, float hi) {
    return (u32)bf16_rne(lo) | ((u32)bf16_rne(hi) << 16);
}
__device__ __forceinline__ float lo16(u32 u) { return __uint_as_float(u << 16); }
__device__ __forceinline__ float hi16(u32 u) { return __uint_as_float(u & 0xFFFF0000u); }

// ---------------------------------------------------------------------------
// MFMA bf16 GEMM: C[M,256] = A[M,256] @ W[256,256]^T + bias, opt rowmask.
// BM=64, BN=128, BK=32, 256 threads (4 waves 2m x 2n), wave tile 32x64.
// Double-buffered LDS, reg-staged, 1 barrier/step. Rotation swizzle:
//   chunk(row,sub) = sub*NR + ((row + 2*sub) mod NR)
// A_F32: A read as f32, packed to bf16 during staging.
// OUT_BF16: bf16 output via LDS bounce; else direct f32 stores.
// MERGED_OUT: blocks with blockIdx.x >= 600 run the small f32 out-GEMM
//   (out = (sum of 4 out_part quarters) @ Wf^T + bias) on 64x64 tiles.
// ---------------------------------------------------------------------------
#define GLOAD(kt) { \
    const int k0 = (kt) * 32; \
    if constexpr (A_F32) { \
        const float* p = (const float*)Aptr + (size_t)(m0 + arow) * 256 + k0 + asub * 8; \
        ra0 = *(const float4*)p; ra1 = *(const float4*)(p + 4); \
    } else { \
        rav = *(const uint4*)((const u16*)Aptr + (size_t)(m0 + arow) * 256 + k0 + asub * 8); \
    } \
    rb0 = *(const uint4*)(W + (size_t)(n0 + b0row) * 256 + k0 + bsub * 8); \
    rb1 = *(const uint4*)(W + (size_t)(n0 + b1row) * 256 + k0 + bsub * 8); }

#define GSTORE(buf) { \
    u16* As = S + (buf) * 6144; \
    u16* Bs = As + 2048; \
    const int ac = asub * 64 + ((arow + 2 * asub) & 63); \
    if constexpr (A_F32) { \
        uint4 o; \
        o.x = pack2(ra0.x, ra0.y); o.y = pack2(ra0.z, ra0.w); \
        o.z = pack2(ra1.x, ra1.y); o.w = pack2(ra1.z, ra1.w); \
        *(uint4*)(As + (ac << 3)) = o; \
    } else { \
        *(uint4*)(As + (ac << 3)) = rav; \
    } \
    *(uint4*)(Bs + ((bsub * 128 + ((b0row + 2 * bsub) & 127)) << 3)) = rb0; \
    *(uint4*)(Bs + ((bsub * 128 + ((b1row + 2 * bsub) & 127)) << 3)) = rb1; }

template<bool A_F32, bool OUT_BF16, bool MERGED_OUT>
__global__ __launch_bounds__(256)
void gemm_bf16(const void* __restrict__ Aptr, const u16* __restrict__ W,
               const float* __restrict__ bias, void* __restrict__ Cout,
               const unsigned char* __restrict__ rowmask,
               const float* __restrict__ Wf,        // f32 Wout (out path)
               const float* __restrict__ opart,     // out_part (out path)
               float* __restrict__ C2)              // out (out path)
{
    __shared__ u16 S[12288];           // 24KB pool
    const int tid = threadIdx.x;

    if constexpr (MERGED_OUT) {
        if (blockIdx.x >= 600) {
            // ---- small f32 out-GEMM: 64x64 tiles, M=600, sum 4 quarters ----
            float (*As2)[68] = reinterpret_cast<float(*)[68]>(S);
            float (*Ws2)[68] = reinterpret_cast<float(*)[68]>((char*)S + 8704);
            const int t20 = blockIdx.x - 600;           // 0..19
            const int m0o = (t20 % 10) * 64;
            const int nq  = (t20 / 10) * 2 + blockIdx.y;
            const int n0o = nq * 64;
            const int tx = tid & 15, ty = tid >> 4;
            const size_t KQS = (size_t)600 * 256;
            float acc[4][4] = {};
            for (int k0 = 0; k0 < 256; k0 += 32) {
#pragma unroll
                for (int i = 0; i < 2; i++) {
                    int t = tid + i * 256;
                    int rr = t >> 3;
                    int c4 = (t & 7) << 2;
                    int ra = min(m0o + rr, 599);
                    const float* p = opart + (size_t)ra * 256 + k0 + c4;
                    float4 v0 = *(const float4*)p;
                    float4 v1 = *(const float4*)(p + KQS);
                    float4 v2 = *(const float4*)(p + 2 * KQS);
                    float4 v3 = *(const float4*)(p + 3 * KQS);
                    float4 va;
                    va.x = (v0.x + v1.x) + (v2.x + v3.x);
                    va.y = (v0.y + v1.y) + (v2.y + v3.y);
                    va.z = (v0.z + v1.z) + (v2.z + v3.z);
                    va.w = (v0.w + v1.w) + (v2.w + v3.w);
                    As2[c4 + 0][rr] = va.x; As2[c4 + 1][rr] = va.y;
                    As2[c4 + 2][rr] = va.z; As2[c4 + 3][rr] = va.w;
                    float4 vw = *(const float4*)(Wf + (size_t)(n0o + rr) * 256 + k0 + c4);
                    Ws2[c4 + 0][rr] = vw.x; Ws2[c4 + 1][rr] = vw.y;
                    Ws2[c4 + 2][rr] = vw.z; Ws2[c4 + 3][rr] = vw.w;
                }
                __syncthreads();
#pragma unroll
                for (int kk = 0; kk < 32; kk++) {
                    float4 a = *(const float4*)&As2[kk][ty * 4];
                    float4 wv4 = *(const float4*)&Ws2[kk][tx * 4];
                    float av[4] = {a.x, a.y, a.z, a.w};
                    float wv[4] = {wv4.x, wv4.y, wv4.z, wv4.w};
#pragma unroll
                    for (int i = 0; i < 4; i++)
#pragma unroll
                        for (int jj = 0; jj < 4; jj++)
                            acc[i][jj] += av[i] * wv[jj];
                }
                __syncthreads();
            }
#pragma unroll
            for (int i = 0; i < 4; i++) {
                int rr = m0o + ty * 4 + i;
                if (rr >= 600) continue;
                int n = n0o + tx * 4;
                float4 o;
                o.x = acc[i][0] + bias[n + 0];
                o.y = acc[i][1] + bias[n + 1];
                o.z = acc[i][2] + bias[n + 2];
                o.w = acc[i][3] + bias[n + 3];
                *(float4*)(C2 + (size_t)rr * 256 + n) = o;
            }
            return;
        }
    }

    const int m0 = blockIdx.x * 64;
    const int n0 = blockIdx.y * 128;
    const int lane = tid & 63;
    const int w = tid >> 6;
    const int wm = w & 1, wn = w >> 1;
    const int g = lane >> 4, r = lane & 15;

    const int arow = tid >> 2, asub = tid & 3;
    const int b0row = tid >> 2;
    const int b1row = 64 + (tid >> 2);
    const int bsub = tid & 3;

    f32x4 acc[2][4];
#pragma unroll
    for (int i = 0; i < 2; i++)
#pragma unroll
        for (int j = 0; j < 4; j++)
            acc[i][j] = (f32x4){0.f, 0.f, 0.f, 0.f};

    float4 ra0, ra1; uint4 rav; uint4 rb0, rb1;

    GLOAD(0);
    GSTORE(0);
    for (int kt = 0; kt < 8; ++kt) {
        if (kt < 7) GLOAD(kt + 1);
        __syncthreads();
        const u16* As = S + (kt & 1) * 6144;
        const u16* Bs = As + 2048;
        bf16x8 af[2], bf[4];
#pragma unroll
        for (int mf = 0; mf < 2; ++mf) {
            int X = wm * 32 + mf * 16 + r;
            af[mf] = *(const bf16x8*)(As + ((g * 64 + ((X + 2 * g) & 63)) << 3));
        }
#pragma unroll
        for (int nf = 0; nf < 4; ++nf) {
            int X = wn * 64 + nf * 16 + r;
            bf[nf] = *(const bf16x8*)(Bs + ((g * 128 + ((X + 2 * g) & 127)) << 3));
        }
#pragma unroll
        for (int mf = 0; mf < 2; ++mf)
#pragma unroll
            for (int nf = 0; nf < 4; ++nf)
                acc[mf][nf] = __builtin_amdgcn_mfma_f32_16x16x32_bf16(
                    af[mf], bf[nf], acc[mf][nf], 0, 0, 0);
        if (kt < 7) GSTORE((kt + 1) & 1);
    }

    if constexpr (!OUT_BF16) {
        float* C = (float*)Cout;
#pragma unroll
        for (int nf = 0; nf < 4; ++nf) {
            int ng = n0 + wn * 64 + nf * 16 + r;
            float bb = bias[ng];
#pragma unroll
            for (int mf = 0; mf < 2; ++mf) {
                int mg = m0 + wm * 32 + mf * 16 + g * 4;
#pragma unroll
                for (int reg = 0; reg < 4; ++reg) {
                    float z = 1.f;
                    if (rowmask && rowmask[mg + reg]) z = 0.f;
                    C[(size_t)(mg + reg) * 256 + ng] = (acc[mf][nf][reg] + bb) * z;
                }
            }
        }
    } else {
        u16* C = (u16*)Cout;
#pragma unroll
        for (int round = 0; round < 2; ++round) {
            __syncthreads();
            if (wn == round) {
#pragma unroll
                for (int nf = 0; nf < 4; ++nf) {
                    int col = nf * 16 + r;
                    float bb = bias[n0 + round * 64 + col];
#pragma unroll
                    for (int mf = 0; mf < 2; ++mf) {
                        int row0 = wm * 32 + mf * 16 + g * 4;
#pragma unroll
                        for (int reg = 0; reg < 4; ++reg) {
                            float z = 1.f;
                            if (rowmask && rowmask[m0 + row0 + reg]) z = 0.f;
                            S[(row0 + reg) * 64 + col] =
                                bf16_rne((acc[mf][nf][reg] + bb) * z);
                        }
                    }
                }
            }
            __syncthreads();
#pragma unroll
            for (int i = 0; i < 2; ++i) {
                int c = tid + i * 256;
                int row = c >> 3, cc = c & 7;
                *(uint4*)(C + (size_t)(m0 + row) * 256 + n0 + round * 64 + cc * 8) =
                    *(const uint4*)(S + row * 64 + cc * 8);
            }
        }
    }
}

// ---------------------------------------------------------------------------
// Merged prep kernel. Blocks 0..63: convert Wv/Wout to bf16.
// Blocks 64..663: per-(b,q) params (aw/ob GEMV + softmaxes + boxes).
// ---------------------------------------------------------------------------
__global__ __launch_bounds__(256)
void prep_kernel(const float* __restrict__ Wv, u16* __restrict__ Wv_b,
                 const float* __restrict__ Wout, u16* __restrict__ Wout_b,
                 const float* __restrict__ query,
                 const float* __restrict__ Wattn, const float* __restrict__ battn,
                 const float* __restrict__ Wbox,  const float* __restrict__ bbox,
                 const float* __restrict__ ref_windows,
                 const float* __restrict__ vvr,
                 float* __restrict__ params)
{
    if (blockIdx.x < 64) {
        const float* src = (blockIdx.x < 32) ? Wv : Wout;
        u16* dst = (blockIdx.x < 32) ? Wv_b : Wout_b;
        int i = ((blockIdx.x & 31) * 256 + threadIdx.x) * 8;
        float4 a = *(const float4*)(src + i);
        float4 b = *(const float4*)(src + i + 4);
        uint4 o;
        o.x = pack2(a.x, a.y); o.y = pack2(a.z, a.w);
        o.z = pack2(b.x, b.y); o.w = pack2(b.z, b.w);
        *(uint4*)(dst + i) = o;
        return;
    }

    __shared__ float qrow[256];
    __shared__ float awob[256];
    __shared__ float4 boxs[8][4];
    __shared__ float wgts[8][4][4];
    __shared__ float cqds[8][4];

    const int bq = blockIdx.x - 64;
    const int b = bq / kQ;
    const int tid = threadIdx.x;

    if (tid < 64)
        ((float4*)qrow)[tid] = ((const float4*)(query + (size_t)bq * 256))[tid];
    __syncthreads();

    {
        const float* Wrow = (tid < 128) ? (Wattn + (size_t)tid * 256)
                                        : (Wbox + (size_t)(tid - 128) * 256);
        float s = (tid < 128) ? battn[tid] : bbox[tid - 128];
#pragma unroll 8
        for (int d4 = 0; d4 < 64; d4++) {
            float4 wv = ((const float4*)Wrow)[d4];
            float4 qv = ((const float4*)qrow)[d4];
            s += wv.x * qv.x + wv.y * qv.y + wv.z * qv.z + wv.w * qv.w;
        }
        awob[tid] = s;
    }
    __syncthreads();

    if (tid < 8) {
        const int h = tid;
        float m = -1e30f;
        float E[16];
#pragma unroll
        for (int i = 0; i < 16; i++) m = fmaxf(m, awob[h * 16 + i]);
        float Ssum = 0.f;
#pragma unroll
        for (int i = 0; i < 16; i++) { E[i] = expf(awob[h * 16 + i] - m); Ssum += E[i]; }
        float invS16 = 1.f / (16.f * Ssum);
#pragma unroll
        for (int qd = 0; qd < 4; qd++) {
            float Sq = E[qd] + E[4 + qd] + E[8 + qd] + E[12 + qd];
            float inv = 1.f / Sq;
#pragma unroll
            for (int l = 0; l < 4; l++) wgts[h][l][qd] = E[l * 4 + qd] * inv;
            cqds[h][qd] = Sq * invS16;
        }
    }
    if (tid >= 64 && tid < 96) {
        const int t = tid - 64;
        const int h = t >> 2, l = t & 3;
        float4 rw = ((const float4*)ref_windows)[bq];
        float ob0 = awob[128 + h * 16 + l * 4 + 0];
        float ob1 = awob[128 + h * 16 + l * 4 + 1];
        float ob2 = awob[128 + h * 16 + l * 4 + 2];
        float ob3 = awob[128 + h * 16 + l * 4 + 3];
        float cx = rw.x + ob0 * 0.125f * rw.z;
        float cy = rw.y + ob1 * 0.125f * rw.w;
        float sx = fmaxf(rw.z + ob2 * 0.125f * rw.z, 0.f);
        float sy = fmaxf(rw.w + ob3 * 0.125f * rw.w, 0.f);
        float vrx = vvr[(b * 4 + l) * 2 + 0];
        float vry = vvr[(b * 4 + l) * 2 + 1];
        boxs[h][l] = make_float4(cx * vrx, cy * vry, sx * vrx, sy * vry);
    }
    __syncthreads();

    float* p = params + (size_t)bq * 288;
    if (tid < 32)       ((float4*)p)[tid] = ((float4*)boxs)[tid];
    else if (tid < 64)  ((float4*)p)[tid] = ((float4*)wgts)[tid - 32];
    else if (tid < 72)  ((float4*)p)[tid] = ((float4*)cqds)[tid - 64];
}

// ---------------------------------------------------------------------------
// Sampler (round-10 proven form): grid 2400; bq = blk % 600, kq = blk / 600
// (siblings differ by 600 = 0 mod 8 -> same XCD L2).
// 512 threads = (klocal 0..15, h 0..7, ch 0..3). One k per thread, acc[8] regs.
// ---------------------------------------------------------------------------
__global__ __launch_bounds__(512)
void sample_bf16(const u16* __restrict__ valb,
                 const float* __restrict__ params,
                 u16* __restrict__ maskb,          // (B*Q*64, 256) bf16
                 float* __restrict__ out_part)     // (2400, 256), [kq*600+bq]
{
    __shared__ float4 boxs[8][4];
    __shared__ float wgts[8][4][4];
    __shared__ float cqds[8][4];
    __shared__ float warr[8][256];

    const int blk = blockIdx.x;
    const int bq = blk % 600;
    const int kq = blk / 600;
    const int b = bq / kQ;
    const int tid = threadIdx.x;

    if (tid < 72) {
        float4 v = ((const float4*)(params + (size_t)bq * 288))[tid];
        if (tid < 32)      ((float4*)boxs)[tid] = v;
        else if (tid < 64) ((float4*)wgts)[tid - 32] = v;
        else               ((float4*)cqds)[tid - 64] = v;
    }
    __syncthreads();

    const int klocal = tid >> 5;            // 0..15
    const int h = (tid >> 2) & 7;           // 0..7
    const int ch = tid & 3;                 // 0..3
    const int k = kq * 16 + klocal;
    const float kx = (float)(k & 7) * 0.125f - 0.4375f;
    const float ky = (float)(k >> 3) * 0.125f - 0.4375f;
    const int qd = (((k >> 5) & 1) << 1) | ((k >> 2) & 1);

    float acc[8];
#pragma unroll
    for (int e = 0; e < 8; e++) acc[e] = 0.f;

    static constexpr int LW[4]  = {128, 64, 32, 16};
    static constexpr int LST[4] = {0, 16384, 20480, 21504};

#pragma unroll
    for (int l = 0; l < 4; l++) {
        const int Wl = LW[l];
        const u16* vbase = valb + ((size_t)(b * kL2 + LST[l]) << 8) + h * 32 + ch * 8;
        float4 bx = boxs[h][l];
        float lw = wgts[h][l][qd];
        float x = (bx.x + kx * bx.z) * Wl - 0.5f;
        float y = (bx.y + ky * bx.w) * Wl - 0.5f;
        float x0f = floorf(x), y0f = floorf(y);
        float dx = x - x0f, dy = y - y0f;
        int x0 = (int)x0f, y0 = (int)y0f;
        int x1 = x0 + 1, y1 = y0 + 1;
        int x0c = min(max(x0, 0), Wl - 1), x1c = min(max(x1, 0), Wl - 1);
        int y0c = min(max(y0, 0), Wl - 1), y1c = min(max(y1, 0), Wl - 1);
        float vx0 = (x0 >= 0 && x0 < Wl) ? 1.f : 0.f;
        float vx1 = (x1 >= 0 && x1 < Wl) ? 1.f : 0.f;
        float vy0 = (y0 >= 0 && y0 < Wl) ? 1.f : 0.f;
        float vy1 = (y1 >= 0 && y1 < Wl) ? 1.f : 0.f;
        float w00 = (1.f - dx) * (1.f - dy) * vx0 * vy0 * lw;
        float w10 = dx * (1.f - dy) * vx1 * vy0 * lw;
        float w01 = (1.f - dx) * dy * vx0 * vy1 * lw;
        float w11 = dx * dy * vx1 * vy1 * lw;
        uint4 v00 = *(const uint4*)(vbase + ((size_t)(y0c * Wl + x0c) << 8));
        uint4 v10 = *(const uint4*)(vbase + ((size_t)(y0c * Wl + x1c) << 8));
        uint4 v01 = *(const uint4*)(vbase + ((size_t)(y1c * Wl + x0c) << 8));
        uint4 v11 = *(const uint4*)(vbase + ((size_t)(y1c * Wl + x1c) << 8));
        acc[0] += w00*lo16(v00.x) + w10*lo16(v10.x) + w01*lo16(v01.x) + w11*lo16(v11.x);
        acc[1] += w00*hi16(v00.x) + w10*hi16(v10.x) + w01*hi16(v01.x) + w11*hi16(v11.x);
        acc[2] += w00*lo16(v00.y) + w10*lo16(v10.y) + w01*lo16(v01.y) + w11*lo16(v11.y);
        acc[3] += w00*hi16(v00.y) + w10*hi16(v10.y) + w01*hi16(v01.y) + w11*hi16(v11.y);
        acc[4] += w00*lo16(v00.z) + w10*lo16(v10.z) + w01*lo16(v01.z) + w11*lo16(v11.z);
        acc[5] += w00*hi16(v00.z) + w10*hi16(v10.z) + w01*hi16(v01.z) + w11*hi16(v11.z);
        acc[6] += w00*lo16(v00.w) + w10*lo16(v10.w) + w01*lo16(v01.w) + w11*lo16(v11.w);
        acc[7] += w00*hi16(v00.w) + w10*hi16(v10.w) + w01*hi16(v01.w) + w11*hi16(v11.w);
    }

    // mask_pre bf16 write
    {
        uint4 o;
        o.x = pack2(acc[0], acc[1]);
        o.y = pack2(acc[2], acc[3]);
        o.z = pack2(acc[4], acc[5]);
        o.w = pack2(acc[6], acc[7]);
        *(uint4*)(maskb + (((size_t)bq * 64 + k) << 8) + h * 32 + ch * 8) = o;
    }

    // spatial partial: c[h][qd(k)] * acc, reduce over klocal
    {
        const int wave = tid >> 6;
        const int lane = tid & 63;
        float c = cqds[h][qd];
#pragma unroll
        for (int e = 0; e < 8; e++) {
            float v = acc[e] * c;
            v += __shfl_xor(v, 32);
            if (lane < 32) warr[wave][h * 32 + ch * 8 + e] = v;
        }
    }
    __syncthreads();
    if (tid < 256) {
        float s = 0.f;
#pragma unroll
        for (int wv = 0; wv < 8; wv++) s += warr[wv][tid];
        out_part[(size_t)blk * 256 + tid] = s;
    }
}

// ---------------------------------------------------------------------------
extern "C" void kernel_launch(void* const* d_in, const int* in_sizes, int n_in,
                              void* d_out, int out_size, void* d_ws, size_t ws_size,
                              hipStream_t stream)
{
    const float* query       = (const float*)d_in[0];
    const float* value       = (const float*)d_in[1];
    const unsigned char* v_mask = (const unsigned char*)d_in[3];
    const float* vvr         = (const float*)d_in[5];
    const float* ref_windows = (const float*)d_in[6];
    const float* Wv    = (const float*)d_in[7];
    const float* bv    = (const float*)d_in[8];
    const float* Wbox  = (const float*)d_in[9];
    const float* bbox  = (const float*)d_in[10];
    const float* Wattn = (const float*)d_in[11];
    const float* battn = (const float*)d_in[12];
    const float* Wout  = (const float*)d_in[13];
    const float* bout  = (const float*)d_in[14];

    // workspace layout (bytes, all 16B aligned)
    char* wsp = (char*)d_ws;
    u16* Wv_b    = (u16*)wsp;                 wsp += (size_t)65536 * 2;
    u16* Wout_b  = (u16*)wsp;                 wsp += (size_t)65536 * 2;
    u16* val_b   = (u16*)wsp;                 wsp += (size_t)11141120 * 2;
    u16* mask_b  = (u16*)wsp;                 wsp += (size_t)9830400 * 2;
    float* params   = (float*)wsp;            wsp += (size_t)600 * 288 * 4;
    float* out_part = (float*)wsp;            wsp += (size_t)2400 * 256 * 4;

    float* out  = (float*)d_out;              // 600*256
    float* mask = out + (size_t)600 * 256;    // 38400*256

    // 1) weight conversion + per-query params (one dispatch)
    prep_kernel<<<664, 256, 0, stream>>>(Wv, Wv_b, Wout, Wout_b,
                                         query, Wattn, battn, Wbox, bbox,
                                         ref_windows, vvr, params);
    // 2) val = value(f32) @ Wv^T + bv (fused convert, masked rows -> 0), bf16 out
    gemm_bf16<true, true, false><<<dim3(680, 2), 256, 0, stream>>>(
        value, Wv_b, bv, val_b, v_mask, nullptr, nullptr, nullptr);
    // 3) sampling -> mask_pre (bf16) + spatial partials
    sample_bf16<<<2400, 512, 0, stream>>>(val_b, params, mask_b, out_part);
    // 4) mask = mask_pre @ Wout^T + bout (f32 out)  +  merged out-GEMM
    gemm_bf16<false, false, true><<<dim3(620, 2), 256, 0, stream>>>(
        mask_b, Wout_b, bout, mask, nullptr, Wout, out_part, out);
}